// Round 5
// baseline (18.772 us; speedup 1.0000x reference)
//
#include <hip/hip_runtime.h>
#include <math.h>

// Problem constants (fixed by setup_inputs): B=8, E=8, F=16, T=2048, k=32
constexpr int Bd = 8;
constexpr int Ed = 8;
constexpr int Fd = 16;
constexpr int Td = 2048;
constexpr int K  = 32;

constexpr int TG   = 16;          // t-groups per block (lanes per f)
constexpr int TPT  = 2;           // t's per thread
constexpr int TT   = TG * TPT;    // 32 t covered per block
constexpr int HALO = K - 1;       // 31
constexpr int WIN  = TT + HALO;   // 63 staged |exo| values per f
constexpr int STRIDE = 66;        // even -> 8B-aligned b64 rows, conflict-tempered

typedef float f32x2 __attribute__((ext_vector_type(2)));

// Algebraic simplification of the reference:
//   product = q*kv; |product| = |q|*|kv|; sign(product)*kv = sign(q)*|kv|
//   out[b][e][f][t] = sign(q) * sum_j softmax_j(|q|*a_j) * a_j,  a_j = |exo| window
//   out[b][e][16][t] = endo[b][e][t]
// Softmax shift: union max M over the two windows (any shift is exact math;
// worst exp2 arg ~ -60, no flush-to-zero risk on den's max term: exp2(~0)=1).
__global__ __launch_bounds__(256, 6) void tca_kernel(
    const float* __restrict__ endo,
    const float* __restrict__ exo,
    const float* __restrict__ w_expand,
    const float* __restrict__ b_expand,
    float* __restrict__ out)
{
    __shared__ float a_s[Fd * STRIDE];   // 16*66*4 = 4224 B

    const int tid = threadIdx.x;
    const int b   = blockIdx.z;
    const int e   = blockIdx.y;
    const int t0  = blockIdx.x * TT;

    const int f  = tid >> 4;   // 0..15
    const int tg = tid & 15;   // 0..15
    const int t  = t0 + tg * TPT;

    // independent loads issued before the barrier
    const f32x2 qv = *reinterpret_cast<const f32x2*>(&endo[(b * Ed + e) * Td + t]);
    const float wf = w_expand[e * Fd + f];
    const float bf = b_expand[e * Fd + f];

    // ---- stage |exo[b, :, t0-31 .. t0+31]| into LDS (zeros for t<0) ----
    {
        const int rowbase = (b * Fd + f) * Td + t0 - HALO;
        #pragma unroll
        for (int k = 0; k < 4; ++k) {
            const int i = tg + k * 16;
            if (i < WIN) {
                const int tt = t0 - HALO + i;
                const float v = (tt >= 0) ? exo[rowbase + i] : 0.f;
                a_s[f * STRIDE + i] = fabsf(v);
            }
        }
    }
    __syncthreads();

    // passthrough channel (slot 16)
    if (f == 0) {
        *reinterpret_cast<f32x2*>(
            &out[(((b * Ed + e) * (Fd + 1)) + Fd) * Td + t]) = qv;
    }

    // ---- union window va[0..32] (+1 pad) via 17 aligned b64 LDS reads ----
    float va[34];
    {
        const f32x2* base = reinterpret_cast<const f32x2*>(&a_s[f * STRIDE + tg * TPT]);
        #pragma unroll
        for (int k = 0; k < 17; ++k) {
            const f32x2 v = base[k];
            va[2 * k]     = v.x;
            va[2 * k + 1] = v.y;
        }
    }
    // NOTE: va[33] may be garbage (LDS row stages only WIN=63 values) — never used.

    // ---- union max over va[0..32], 4 independent chains ----
    float x0 = va[0], x1 = va[1], x2 = va[2], x3 = va[3];
    #pragma unroll
    for (int j = 4; j < 32; j += 4) {
        x0 = fmaxf(x0, va[j]);
        x1 = fmaxf(x1, va[j + 1]);
        x2 = fmaxf(x2, va[j + 2]);
        x3 = fmaxf(x3, va[j + 3]);
    }
    const float M = fmaxf(fmaxf(x0, x1), fmaxf(x2, fmaxf(x3, va[32])));

    constexpr float LOG2E = 1.44269504088896340736f;
    const float q0  = fmaf(qv.x, wf, bf);
    const float q1  = fmaf(qv.y, wf, bf);
    const float c1a = fabsf(q0) * LOG2E;   // exp(|q|*(a-M)) == exp2(a*c1 + c0)
    const float c0a = -M * c1a;
    const float c1b = fabsf(q1) * LOG2E;
    const float c0b = -M * c1b;
    const float s0  = (q0 > 0.f) ? 1.f : ((q0 < 0.f) ? -1.f : 0.f);
    const float s1  = (q1 > 0.f) ? 1.f : ((q1 < 0.f) ? -1.f : 0.f);

    // ---- 8 independent accumulation chains: 2 p-streams x 2 j-phases ----
    float den00 = 0.f, den01 = 0.f, num00 = 0.f, num01 = 0.f;
    float den10 = 0.f, den11 = 0.f, num10 = 0.f, num11 = 0.f;

    #pragma unroll
    for (int j = 0; j < K; j += 2) {
        const float a0 = va[j];
        const float a1 = va[j + 1];
        const float a2 = va[j + 2];
        const float e00 = __builtin_amdgcn_exp2f(fmaf(a0, c1a, c0a));
        const float e01 = __builtin_amdgcn_exp2f(fmaf(a1, c1a, c0a));
        const float e10 = __builtin_amdgcn_exp2f(fmaf(a1, c1b, c0b));
        const float e11 = __builtin_amdgcn_exp2f(fmaf(a2, c1b, c0b));
        den00 += e00;
        num00 = fmaf(e00, a0, num00);
        den01 += e01;
        num01 = fmaf(e01, a1, num01);
        den10 += e10;
        num10 = fmaf(e10, a1, num10);
        den11 += e11;
        num11 = fmaf(e11, a2, num11);
    }

    const float den0 = den00 + den01;   // >= 1 (max term -> exp2(~0) = 1)
    const float den1 = den10 + den11;
    const float num0 = num00 + num01;
    const float num1 = num10 + num11;

    f32x2 r;
    r.x = s0 * num0 * __builtin_amdgcn_rcpf(den0);
    r.y = s1 * num1 * __builtin_amdgcn_rcpf(den1);
    *reinterpret_cast<f32x2*>(
        &out[(((b * Ed + e) * (Fd + 1)) + f) * Td + t]) = r;
}

extern "C" void kernel_launch(void* const* d_in, const int* in_sizes, int n_in,
                              void* d_out, int out_size, void* d_ws, size_t ws_size,
                              hipStream_t stream) {
    const float* endo = (const float*)d_in[0];
    const float* exo  = (const float*)d_in[1];
    const float* w    = (const float*)d_in[2];
    const float* bb   = (const float*)d_in[3];
    float* out = (float*)d_out;

    dim3 grid(Td / TT, Ed, Bd);   // (64, 8, 8) = 4096 blocks
    tca_kernel<<<grid, 256, 0, stream>>>(endo, exo, w, bb, out);
}